// Round 10
// baseline (70.675 us; speedup 1.0000x reference)
//
#include <hip/hip_runtime.h>

// DecisionTreePolicy — complete binary tree, depth 15 (32767 nodes).
// Internal 0..16382 (children 2i+1/2i+2), leaves 16383..32766 -> exactly 14
// decisions from root; out[b] = leaf_logits[leaf(b)].
//
// History: R1/R2 gathers 84us. R4 LDS-stream 68.5. R5 16-wave 78. R6
// vmcnt(0) 80. R7 depth-2 counted-vmcnt 67.2 (best). R8 prod/cons 70.6.
// R9 depth-4 68.9 -> pipelining depth is NOT the limiter.
// R10 = R7 schedule + two LDS-pipe fixes:
//  (a) rotation swizzle on the obs tile: linear layout put row r, feature f
//      at bank (f&31) independent of r -> converged tree levels (uniform f)
//      were a 32-way conflict (~11x) on every ds_read, ~15us total. New
//      layout: chunk slot (c + (r>>2))&63, elements rotated by r&3 ->
//      bank = 4*((f>>2 + r>>2)&7) + ((f+r)&3), bijective over 32 rows.
//  (b) paired-children tree: sthr2[n]={thr[2n+1],thr[2n+2]} (one b64) +
//      sfeat2[n] u8-pair (one u16) -> 2 LDS reads/level instead of 4.

#define N_PAIR    8191      // parents of internal children: nodes 0..8190
#define N_FEAT    256
#define N_ACT     64
#define BATCH     262144
#define BLOCK     256
#define GRID      256
#define ROWS_PB   (BATCH / GRID)      // 1024 rows per block
#define HROWS     32                  // rows per half-tile (32 KB)
#define HALVES    (ROWS_PB / HROWS)   // 32
#define DEPTH     14
#define PFN       8                   // f32x4 per thread per half-tile
#define TSLOTS    (HROWS * N_FEAT / 4)  // 2048 f32x4 per half-tile

typedef float f32x4 __attribute__((ext_vector_type(4)));

// Store PFN register chunks into buf with the rotation swizzle.
// ROT = r&3 = waveid (wave-uniform), so element shuffles are compile-time.
template<int ROT>
__device__ __forceinline__ void store_rot(f32x4* dst, const f32x4 (&pf)[PFN], int tid) {
#pragma unroll
    for (int k = 0; k < PFN; ++k) {
        const int s = k * BLOCK + tid;      // global chunk id: row r, chunk c
        const int r = s >> 6;
        const int c = s & 63;
        const f32x4 v = pf[k];
        f32x4 w;                            // w[(e+r)&3] = v[e]  ->  w[j] = v[(j-ROT)&3]
        w.x = v[(0 - ROT) & 3];
        w.y = v[(1 - ROT) & 3];
        w.z = v[(2 - ROT) & 3];
        w.w = v[(3 - ROT) & 3];
        dst[r * 64 + ((c + (r >> 2)) & 63)] = w;
    }
}

__global__ __launch_bounds__(BLOCK, 1) void tree_policy_kernel(
    const float* __restrict__ obs,          // [BATCH][N_FEAT]
    const int*   __restrict__ features,     // [N_NODES]
    const float* __restrict__ thresholds,   // [N_NODES]
    const float* __restrict__ leaf_logits,  // [N_NODES][N_ACT]
    float*       __restrict__ out)          // [BATCH][N_ACT]
{
    __shared__ float2         sthr2 [N_PAIR];       // 65528 B
    __shared__ unsigned short sfeat2[N_PAIR];       // 16382 B
    __shared__ __align__(16) f32x4 buf[2][TSLOTS];  // 2 x 32 KB; total ~147.4 KB

    const int tid  = threadIdx.x;
    const int lane = tid & 63;
    const long rowBase = (long)blockIdx.x * ROWS_PB;
    const f32x4* gsrc = (const f32x4*)(obs + rowBase * N_FEAT);

    // ---- tree -> LDS, paired-children layout (one-time, L2/L3-sourced) ----
    for (int i = tid; i < N_PAIR; i += BLOCK) {
        sthr2[i]  = make_float2(thresholds[2 * i + 1], thresholds[2 * i + 2]);
        sfeat2[i] = (unsigned short)((features[2 * i + 1] & 255) |
                                     ((features[2 * i + 2] & 255) << 8));
    }
    const float thr_root  = thresholds[0];
    const int   feat_root = features[0];

    // ---- prologue: fill the depth-2 pipe (halves 0 and 1) ----
    f32x4 pfA[PFN], pfB[PFN];
#pragma unroll
    for (int k = 0; k < PFN; ++k)
        pfA[k] = __builtin_nontemporal_load(&gsrc[0 * TSLOTS + k * BLOCK + tid]);
#pragma unroll
    for (int k = 0; k < PFN; ++k)
        pfB[k] = __builtin_nontemporal_load(&gsrc[1 * TSLOTS + k * BLOCK + tid]);

    asm volatile("s_waitcnt lgkmcnt(0)" ::: "memory");   // tree ds_writes done
    __builtin_amdgcn_s_barrier();                        // tree visible to all waves

    const int r    = lane & 31;     // this lane's row within a half-tile (2x dup)
    const int rq   = r >> 2;
    const int rbase = r * 256;

    auto half_body = [&](int h, f32x4 (&pf)[PFN]) {
        const int b = h & 1;
        // (1) counted wait: loads(h) retired; younger (other group's 8 loads +
        // prev epilogue's 4 ops) stay in flight. In-order vmcnt retirement.
        if (h == 0 || h == HALVES - 1)
            asm volatile("s_waitcnt vmcnt(8)" ::: "memory");
        else
            asm volatile("s_waitcnt vmcnt(12)" ::: "memory");
        __builtin_amdgcn_sched_barrier(0);
        // (2) regs -> LDS, rotation-swizzled (wave-uniform dispatch on r&3=waveid)
        switch (tid >> 6) {
            case 0: store_rot<0>(&buf[b][0], pf, tid); break;
            case 1: store_rot<1>(&buf[b][0], pf, tid); break;
            case 2: store_rot<2>(&buf[b][0], pf, tid); break;
            default: store_rot<3>(&buf[b][0], pf, tid); break;
        }
        // (3) re-issue this register group for half h+2
        if (h + 2 < HALVES) {
#pragma unroll
            for (int k = 0; k < PFN; ++k)
                pf[k] = __builtin_nontemporal_load(
                    &gsrc[(long)(h + 2) * TSLOTS + k * BLOCK + tid]);
        }
        asm volatile("s_waitcnt lgkmcnt(0)" ::: "memory");  // my ds_writes committed
        __builtin_amdgcn_s_barrier();                        // buf[b] visible (1 barrier/half:
        __builtin_amdgcn_sched_barrier(0);                   // write(h) vs read(h-2) separated)

        // (4) traversal: paired-children reads + swizzled obs lookup.
        //     Per level: 1 b32 (obs) + 1 b64 (thr pair) + 1 u16 (feat pair),
        //     obs read conflict-free even when fcur is wave-uniform.
        const float* bufc = (const float*)&buf[b][0];
        int   node = 0;
        float tcur = thr_root;
        int   fcur = feat_root;
#pragma unroll
        for (int d = 0; d < DEPTH - 1; ++d) {
            const float x = bufc[rbase + ((((fcur >> 2) + rq) & 63) << 2) + ((fcur + r) & 3)];
            const float2   tch = sthr2[node];
            const unsigned fp  = sfeat2[node];
            const bool L = (x <= tcur);            // reference NaN semantics
            node = 2 * node + (L ? 1 : 2);
            tcur = L ? tch.x : tch.y;
            fcur = (int)(L ? (fp & 255u) : (fp >> 8));
        }
        {   // last decision peeled: children are leaves (no LDS entries)
            const float x = bufc[rbase + ((((fcur >> 2) + rq) & 63) << 2) + ((fcur + r) & 3)];
            node = 2 * node + ((x <= tcur) ? 1 : 2);
        }
        // node = leaf id in [16383, 32766]

        // (5) epilogue: 32 rows x 16 chunks = 512 f32x4, 2 per thread
        const long outRow0 = rowBase + (long)h * HROWS;
#pragma unroll
        for (int j = 0; j < 2; ++j) {
            const int fid   = j * BLOCK + tid;
            const int rr    = fid >> 4;
            const int chunk = fid & 15;
            const int leaf  = __shfl(node, rr, 64);   // lane rr holds row rr
            const f32x4 v   = *(const f32x4*)(leaf_logits + (size_t)leaf * N_ACT + chunk * 4);
            __builtin_nontemporal_store(v, (f32x4*)(out + (outRow0 + rr) * N_ACT + chunk * 4));
        }
    };

    for (int hh = 0; hh < HALVES; hh += 2) {
        half_body(hh,     pfA);
        half_body(hh + 1, pfB);
    }
}

extern "C" void kernel_launch(void* const* d_in, const int* in_sizes, int n_in,
                              void* d_out, int out_size, void* d_ws, size_t ws_size,
                              hipStream_t stream) {
    const float* obs         = (const float*)d_in[0];
    const int*   features    = (const int*)  d_in[1];
    const float* thresholds  = (const float*)d_in[2];
    // d_in[3]/d_in[4] (children) unused: tree is complete by construction.
    const float* leaf_logits = (const float*)d_in[5];
    float*       out         = (float*)d_out;

    tree_policy_kernel<<<dim3(GRID), dim3(BLOCK), 0, stream>>>(
        obs, features, thresholds, leaf_logits, out);
}

// Round 11
// 64.535 us; speedup vs baseline: 1.0951x; 1.0951x over previous
//
#include <hip/hip_runtime.h>

// DecisionTreePolicy — complete binary tree, depth 15 (32767 nodes).
// Internal 0..16382 (children 2i+1/2i+2), leaves 16383..32766 -> exactly 14
// decisions from root; out[b] = leaf_logits[leaf(b)].
//
// History: R1/R2 gathers 84us. R4 LDS-stream 68.5. R5 16-wave full-redundancy
// 78 (LDS-inst scaling). R6 vmcnt(0) 80. R7 depth-2 counted-vmcnt 67.2 (best).
// R8 prod/cons 70.6. R9 depth-4 68.9 (outstanding-bytes not the limit).
// R10 swizzle+paired 70.7 (bank conflicts not the limit).
// R11: the un-attacked axis — waves/SIMD. All prior best ran 1 wave/SIMD, so
// the 13-level dependent LDS chain (~0.65us) + gather latency per half were
// fully exposed. Now BLOCK=512 (2 waves/SIMD) with rows PARTITIONED per wave
// (wave w owns rows 4w..4w+3; 16 lanes/row in-wave broadcast) -> LDS insts
// only 2x R7 (312/half, ~0.78us < 1.63us HBM budget), chains hide under the
// co-resident wave, and the epilogue needs no __shfl (each lane holds its
// row's leaf). Schedule unchanged: R7 depth-2 counted-vmcnt, linear layout.

#define N_INTERN  16383
#define N_FEAT    256
#define N_ACT     64
#define BATCH     262144
#define BLOCK     512
#define GRID      256
#define ROWS_PB   (BATCH / GRID)      // 1024 rows per block
#define HROWS     32                  // rows per half-tile (32 KB)
#define HALVES    (ROWS_PB / HROWS)   // 32
#define DEPTH     14
#define PFN       4                   // f32x4 per thread per half: 32KB/512thr/16B
#define TSLOTS    (HROWS * N_FEAT / 4)  // 2048 f32x4 per half-tile

typedef float f32x4 __attribute__((ext_vector_type(4)));

__global__ __launch_bounds__(BLOCK, 1) void tree_policy_kernel(
    const float* __restrict__ obs,          // [BATCH][N_FEAT]
    const int*   __restrict__ features,     // [N_NODES]
    const float* __restrict__ thresholds,   // [N_NODES]
    const float* __restrict__ leaf_logits,  // [N_NODES][N_ACT]
    float*       __restrict__ out)          // [BATCH][N_ACT]
{
    __shared__ float         sthr [N_INTERN];        // 64 KB
    __shared__ unsigned char sfeat[N_INTERN];        // 16 KB
    __shared__ __align__(16) f32x4 buf[2][TSLOTS];   // 2 x 32 KB -> ~144 KB total

    const int tid  = threadIdx.x;
    const int lane = tid & 63;
    const int wave = tid >> 6;                // 0..7
    const long rowBase = (long)blockIdx.x * ROWS_PB;
    const f32x4* gsrc = (const f32x4*)(obs + rowBase * N_FEAT);

    // ---- tree -> LDS (one-time; compiler manages waits) ----
    for (int i = tid; i < N_INTERN; i += BLOCK) {
        sthr[i]  = thresholds[i];
        sfeat[i] = (unsigned char)features[i];
    }
    const float thr_root  = thresholds[0];
    const int   feat_root = features[0];

    // ---- prologue: fill the depth-2 pipe (halves 0 and 1) ----
    f32x4 pfA[PFN], pfB[PFN];
#pragma unroll
    for (int k = 0; k < PFN; ++k)
        pfA[k] = __builtin_nontemporal_load(&gsrc[0 * TSLOTS + k * BLOCK + tid]);
#pragma unroll
    for (int k = 0; k < PFN; ++k)
        pfB[k] = __builtin_nontemporal_load(&gsrc[1 * TSLOTS + k * BLOCK + tid]);

    asm volatile("s_waitcnt lgkmcnt(0)" ::: "memory");   // tree ds_writes done
    __builtin_amdgcn_s_barrier();                        // tree visible to all waves

    // Row ownership: wave w covers rows [4w, 4w+4); 16 lanes duplicate a row.
    const int myrow_id = (wave << 2) | (lane >> 4);   // 0..31
    const int chunk    = lane & 15;                   // this lane's f32x4 chunk

    auto half_body = [&](int h, f32x4 (&pf)[PFN]) {
        const int b = h & 1;
        // (1) counted wait: loads(h) retired. Younger per wave (steady state):
        // other group's 4 loads + previous epilogue's 1 gather + 1 store = 6.
        if (h == 0)                 asm volatile("s_waitcnt vmcnt(4)" ::: "memory");
        else if (h == HALVES - 1)   asm volatile("s_waitcnt vmcnt(2)" ::: "memory");
        else                        asm volatile("s_waitcnt vmcnt(6)" ::: "memory");
        __builtin_amdgcn_sched_barrier(0);
        // (2) regs -> LDS (linear layout)
#pragma unroll
        for (int k = 0; k < PFN; ++k)
            buf[b][k * BLOCK + tid] = pf[k];
        // (3) re-issue this register group for half h+2
        if (h + 2 < HALVES) {
#pragma unroll
            for (int k = 0; k < PFN; ++k)
                pf[k] = __builtin_nontemporal_load(
                    &gsrc[(long)(h + 2) * TSLOTS + k * BLOCK + tid]);
        }
        asm volatile("s_waitcnt lgkmcnt(0)" ::: "memory");  // my ds_writes committed
        __builtin_amdgcn_s_barrier();                        // buf[b] visible (write(h)
        __builtin_amdgcn_sched_barrier(0);                   //  vs read(h-2) separated)

        // (4) traversal: child-prefetch form — obs lookup (fcur in register)
        //     runs parallel to children's thr/feat reads: 1 LDS round/level.
        //     2 waves/SIMD hide each other's dependent chains.
        const float* myrow = (const float*)&buf[b][0] + myrow_id * N_FEAT;
        int   node = 0;
        float tcur = thr_root;
        int   fcur = feat_root;
#pragma unroll
        for (int d = 0; d < DEPTH - 1; ++d) {
            const float x   = myrow[fcur];
            const int   c   = 2 * node + 1;
            const float tl  = sthr[c];
            const float trr = sthr[c + 1];
            const int   fl  = sfeat[c];
            const int   fr  = sfeat[c + 1];
            const bool  L   = (x <= tcur);          // reference NaN semantics
            node = L ? c : c + 1;
            tcur = L ? tl : trr;
            fcur = L ? fl : fr;
        }
        {   // last decision peeled: children are leaves (no LDS entries)
            const float x = myrow[fcur];
            node = 2 * node + ((x <= tcur) ? 1 : 2);
        }
        // node = this row's leaf id — every duplicate lane holds it directly.

        // (5) epilogue: no shfl needed. Lane -> (row, chunk); 16-lane groups
        //     store 256 B contiguous; 1 gather + 1 store per thread.
        const long orow = rowBase + (long)h * HROWS + myrow_id;
        const f32x4 v = *(const f32x4*)(leaf_logits + (size_t)node * N_ACT + chunk * 4);
        __builtin_nontemporal_store(v, (f32x4*)(out + orow * N_ACT + chunk * 4));
    };

    for (int hh = 0; hh < HALVES; hh += 2) {
        half_body(hh,     pfA);
        half_body(hh + 1, pfB);
    }
}

extern "C" void kernel_launch(void* const* d_in, const int* in_sizes, int n_in,
                              void* d_out, int out_size, void* d_ws, size_t ws_size,
                              hipStream_t stream) {
    const float* obs         = (const float*)d_in[0];
    const int*   features    = (const int*)  d_in[1];
    const float* thresholds  = (const float*)d_in[2];
    // d_in[3]/d_in[4] (children) unused: tree is complete by construction.
    const float* leaf_logits = (const float*)d_in[5];
    float*       out         = (float*)d_out;

    tree_policy_kernel<<<dim3(GRID), dim3(BLOCK), 0, stream>>>(
        obs, features, thresholds, leaf_logits, out);
}